// Round 5
// baseline (125.871 us; speedup 1.0000x reference)
//
#include <hip/hip_runtime.h>
#include <hip/hip_bf16.h>
#include <cstdint>
#include <cstddef>

// Problem constants (B=4, H=16, S=4096, E=128)
#define S_LEN 4096
#define E_DIM 128
#define NROWS (4 * 16 * 4096)   // 262144 token rows
#define T_STEPS 4               // s-steps per block (software-pipelined)

typedef __attribute__((ext_vector_type(8))) short bh8;   // 8 bf16 (4 VGPRs) MFMA frag
typedef __attribute__((ext_vector_type(4))) float f4;    // MFMA accumulator

__device__ __forceinline__ unsigned short f2bf(float f) {
    union { float f; uint32_t u; } v; v.f = f;
    uint32_t r = v.u + 0x7FFFu + ((v.u >> 16) & 1u);   // round-to-nearest-even
    return (unsigned short)(r >> 16);
}

__device__ __forceinline__ short bfc(float f) {          // compiler-friendly cast
    __hip_bfloat16 h = __float2bfloat16(f);
    return *reinterpret_cast<short*>(&h);
}

// ---------- prologue: A = (S - S^T)/2, plus interleaved cos/sin table ----------
// csT[s*128 + 2*f] = cos(pos[s]*freq[f]),  csT[s*128 + 2*f + 1] = sin(...)
__global__ void k_prep(const float* __restrict__ Sc, const float* __restrict__ pos,
                       float* __restrict__ A, float* __restrict__ csT) {
    int b = blockIdx.x;
    if (b < 16) {
        for (int e = b * 256 + threadIdx.x; e < 16384; e += 4096) {
            int i = e >> 7, j = e & 127;
            A[e] = 0.5f * (Sc[i * 128 + j] - Sc[j * 128 + i]);
        }
    } else {
        int t = (b - 16) * 256 + threadIdx.x;
        for (int e = t; e < S_LEN * 64; e += 256 * 256) {
            int s = e >> 6, f = e & 63;
            // freq = 10000^(-f/64) = exp2(-f * log2(10000)/64)
            float freq = exp2f(-0.20762050593046015f * (float)f);
            float ang = pos[s] * freq;
            float sv, cv;
            sincosf(ang, &sv, &cv);
            csT[s * 128 + 2 * f]     = cv;
            csT[s * 128 + 2 * f + 1] = sv;
        }
    }
}

// ---------- A2 = A*A (f32, tiny) ----------
__global__ void k_sq(const float* __restrict__ M, float* __restrict__ O) {
    int t = blockIdx.x * 256 + threadIdx.x;      // 32 blocks
    for (int e = t; e < 16384; e += 8192) {
        int i = e >> 7, j = e & 127;
        float acc = 0.f;
        for (int k = 0; k < 128; ++k) acc += M[i * 128 + k] * M[k * 128 + j];
        O[e] = acc;
    }
}

// ---------- A4 = A2*A2  and  M1 = (I - 2A + A2)(I + A2) ----------
__global__ void k_step2(const float* __restrict__ A, const float* __restrict__ A2,
                        float* __restrict__ A4, float* __restrict__ M1) {
    int b = blockIdx.x;                          // 64 blocks
    if (b < 32) {
        int t = b * 256 + threadIdx.x;
        for (int e = t; e < 16384; e += 8192) {
            int i = e >> 7, j = e & 127;
            float acc = 0.f;
            for (int k = 0; k < 128; ++k) acc += A2[i * 128 + k] * A2[k * 128 + j];
            A4[e] = acc;
        }
    } else {
        int t = (b - 32) * 256 + threadIdx.x;
        for (int e = t; e < 16384; e += 8192) {
            int i = e >> 7, j = e & 127;
            float acc = 0.f;
            for (int k = 0; k < 128; ++k) {
                float bik = A2[i * 128 + k] - 2.0f * A[i * 128 + k] + (k == i ? 1.0f : 0.0f);
                float ckj = A2[k * 128 + j] + (k == j ? 1.0f : 0.0f);
                acc += bik * ckj;
            }
            M1[e] = acc;
        }
    }
}

// ---------- P = M1*(I + A4);  store Q = P - I as bf16 ----------
__global__ void k_finalP(const float* __restrict__ M1, const float* __restrict__ A4,
                         unsigned short* __restrict__ Qb) {
    int t = blockIdx.x * 256 + threadIdx.x;      // 32 blocks
    for (int e = t; e < 16384; e += 8192) {
        int i = e >> 7, j = e & 127;
        float acc = M1[e];
        for (int k = 0; k < 128; ++k) acc += M1[i * 128 + k] * A4[k * 128 + j];
        if (i == j) acc -= 1.0f;                 // Q = P - I
        Qb[e] = f2bf(acc);
    }
}

// ---------- main fused kernel: out = RoPE(x + x*Q^T) ----------
// Same-s tiling: wave handles 16 (b,h) rows at one s; block = 64 bh x T_STEPS s.
//   token m = bh*4096 + s, bh = wave*16+llo, s = blockIdx*T + step.
//   -> csT reads are wave-broadcast (512 B/tile instead of 8 KB).
// Software pipeline: step+1's x-loads issued before step's convert/MFMA/epilogue.
// Swapped MFMA: acc[t] = D[n][m]; lane holds token m (col) -> f4 epilogue.
// Q in LDS, 32 KB, XOR chunk swizzle (R3-verified, 0 bank conflicts).
__global__ __launch_bounds__(256, 4) void k_main(const float* __restrict__ x,
        const unsigned short* __restrict__ Qb,
        const float* __restrict__ csT,
        float* __restrict__ out) {
    __shared__ unsigned short Plds[128 * 128];
    #pragma unroll
    for (int i = 0; i < 8; ++i) {
        int chunk = i * 256 + threadIdx.x;       // 2048 chunks of 8 shorts (16 B)
        int row = chunk >> 4, c = chunk & 15;
        int pc = c ^ (row & 15);
        bh8 v = *(const bh8*)(Qb + chunk * 8);
        *(bh8*)(&Plds[row * 128 + pc * 8]) = v;
    }

    const int wave = threadIdx.x >> 6;
    const int lane = threadIdx.x & 63;
    const int lhi = lane >> 4, llo = lane & 15;
    const int bh = wave * 16 + llo;
    const int s0 = blockIdx.x * T_STEPS;

    // this lane's token rows: consecutive rows starting at (bh, s0)
    const float* xrow = x + ((size_t)bh * S_LEN + s0) * E_DIM;
    float* orow0 = out + ((size_t)bh * S_LEN + s0) * E_DIM;

    // preload step 0's x in frag layout (cols kk*32 + lhi*8 .. +7)
    f4 xa[8];
    {
        const float* p = xrow + lhi * 8;
        #pragma unroll
        for (int kk = 0; kk < 4; ++kk) {
            xa[2 * kk]     = *(const f4*)(p + kk * 32);
            xa[2 * kk + 1] = *(const f4*)(p + kk * 32 + 4);
        }
    }
    __syncthreads();

    #pragma unroll
    for (int step = 0; step < T_STEPS; ++step) {
        const int s = s0 + step;
        const float* rcur = xrow + (size_t)step * E_DIM;

        // prefetch next step's x (issued before compute -> overlaps MFMA+epilogue)
        f4 xn[8];
        if (step + 1 < T_STEPS) {
            const float* p = rcur + E_DIM + lhi * 8;
            #pragma unroll
            for (int kk = 0; kk < 4; ++kk) {
                xn[2 * kk]     = *(const f4*)(p + kk * 32);
                xn[2 * kk + 1] = *(const f4*)(p + kk * 32 + 4);
            }
        }

        // convert current x to bf16 B-fragments
        bh8 frag[4];
        #pragma unroll
        for (int kk = 0; kk < 4; ++kk) {
            bh8 a;
            #pragma unroll
            for (int j = 0; j < 4; ++j) {
                a[j]     = bfc(xa[2 * kk][j]);
                a[4 + j] = bfc(xa[2 * kk + 1][j]);
            }
            frag[kk] = a;
        }

        f4 acc[8];
        #pragma unroll
        for (int t = 0; t < 8; ++t) { f4 z = {0.f, 0.f, 0.f, 0.f}; acc[t] = z; }

        // A-operand = Q rows from LDS: Q[n = t*16+llo][k = kk*32+lhi*8+e]
        #pragma unroll
        for (int kk = 0; kk < 4; ++kk) {
            #pragma unroll
            for (int t = 0; t < 8; ++t) {
                int pc = (kk * 4 + lhi) ^ llo;   // row&15 == llo
                bh8 qfrag = *(const bh8*)(&Plds[(t * 16 + llo) * 128 + pc * 8]);
                acc[t] = __builtin_amdgcn_mfma_f32_16x16x32_bf16(qfrag, frag[kk], acc[t], 0, 0, 0);
            }
        }

        // epilogue: xt = x + x*Q^T, rotate-half RoPE; all float4.
        float* orow = orow0 + (size_t)step * E_DIM;
        const float* csp = csT + (size_t)s * 128;
        #pragma unroll
        for (int t = 0; t < 4; ++t) {
            const int n0 = t * 16 + lhi * 4;     // 4 consecutive n in regs r=0..3
            f4 xlo = *(const f4*)(rcur + n0);
            f4 xhi = *(const f4*)(rcur + n0 + 64);
            // {cos f, sin f, cos f+1, sin f+1}, f = n0/2 — broadcast across llo lanes
            f4 cs_lo = *(const f4*)(csp + n0);
            f4 cs_hi = *(const f4*)(csp + 64 + n0);
            f4 olo, ohi;
            #pragma unroll
            for (int r = 0; r < 4; ++r) {
                float xt1 = acc[t][r] + xlo[r];          // n = n0+r
                float xt2 = acc[t + 4][r] + xhi[r];      // n+64
                float c1 = cs_lo[(r >> 1) * 2], s1 = cs_lo[(r >> 1) * 2 + 1];
                float c2 = cs_hi[(r >> 1) * 2], s2 = cs_hi[(r >> 1) * 2 + 1];
                olo[r] = xt1 * c1 - xt2 * s1;
                ohi[r] = xt2 * c2 + xt1 * s2;
            }
            *(f4*)(orow + n0) = olo;
            *(f4*)(orow + n0 + 64) = ohi;
        }

        // rotate pipeline registers (renamed away by full unroll)
        #pragma unroll
        for (int i = 0; i < 8; ++i) xa[i] = xn[i];
    }
}

extern "C" void kernel_launch(void* const* d_in, const int* in_sizes, int n_in,
                              void* d_out, int out_size, void* d_ws, size_t ws_size,
                              hipStream_t stream) {
    const float* x   = (const float*)d_in[0];
    const float* pos = (const float*)d_in[1];
    const float* Sc  = (const float*)d_in[2];
    float* out = (float*)d_out;

    char* ws = (char*)d_ws;
    float* A            = (float*)(ws);                    // 64 KB
    float* A2           = (float*)(ws + 65536);            // 64 KB
    float* A4           = (float*)(ws + 131072);           // 64 KB
    float* M1           = (float*)(ws + 196608);           // 64 KB
    unsigned short* Qb  = (unsigned short*)(ws + 262144);  // 32 KB bf16
    float* csT          = (float*)(ws + 294912);           // 2 MB interleaved cos/sin

    k_prep<<<272, 256, 0, stream>>>(Sc, pos, A, csT);
    k_sq<<<32, 256, 0, stream>>>(A, A2);
    k_step2<<<64, 256, 0, stream>>>(A, A2, A4, M1);
    k_finalP<<<32, 256, 0, stream>>>(M1, A4, Qb);
    k_main<<<S_LEN / T_STEPS, 256, 0, stream>>>(x, Qb, csT, out);
}

// Round 6
// 108.630 us; speedup vs baseline: 1.1587x; 1.1587x over previous
//
#include <hip/hip_runtime.h>
#include <hip/hip_bf16.h>
#include <cstdint>
#include <cstddef>

// Problem constants (B=4, H=16, S=4096, E=128)
#define S_LEN 4096
#define E_DIM 128
#define NROWS (4 * 16 * 4096)   // 262144 token rows
#define TOK_TILE 64             // tokens per LDS tile (32 KB f32)
#define GRID_MAIN 512
#define TILES_PER_BLOCK (NROWS / TOK_TILE / GRID_MAIN)   // 8

typedef __attribute__((ext_vector_type(8))) short bh8;   // 8 bf16 (4 VGPRs) MFMA frag
typedef __attribute__((ext_vector_type(4))) float f4;    // MFMA accumulator

__device__ __forceinline__ unsigned short f2bf(float f) {
    union { float f; uint32_t u; } v; v.f = f;
    uint32_t r = v.u + 0x7FFFu + ((v.u >> 16) & 1u);   // round-to-nearest-even
    return (unsigned short)(r >> 16);
}

__device__ __forceinline__ short bfc(float f) {          // compiler-friendly cast
    __hip_bfloat16 h = __float2bfloat16(f);
    return *reinterpret_cast<short*>(&h);
}

// ---------- prologue: A = (S - S^T)/2, plus interleaved cos/sin table ----------
// csT[s*128 + 2*f] = cos(pos[s]*freq[f]),  csT[s*128 + 2*f + 1] = sin(...)
__global__ void k_prep(const float* __restrict__ Sc, const float* __restrict__ pos,
                       float* __restrict__ A, float* __restrict__ csT) {
    int b = blockIdx.x;
    if (b < 16) {
        for (int e = b * 256 + threadIdx.x; e < 16384; e += 4096) {
            int i = e >> 7, j = e & 127;
            A[e] = 0.5f * (Sc[i * 128 + j] - Sc[j * 128 + i]);
        }
    } else {
        int t = (b - 16) * 256 + threadIdx.x;
        for (int e = t; e < S_LEN * 64; e += 256 * 256) {
            int s = e >> 6, f = e & 63;
            float freq = exp2f(-0.20762050593046015f * (float)f);
            float ang = pos[s] * freq;
            float sv, cv;
            sincosf(ang, &sv, &cv);
            csT[s * 128 + 2 * f]     = cv;
            csT[s * 128 + 2 * f + 1] = sv;
        }
    }
}

// ---------- A2 = A*A (f32, tiny) ----------
__global__ void k_sq(const float* __restrict__ M, float* __restrict__ O) {
    int t = blockIdx.x * 256 + threadIdx.x;      // 32 blocks
    for (int e = t; e < 16384; e += 8192) {
        int i = e >> 7, j = e & 127;
        float acc = 0.f;
        for (int k = 0; k < 128; ++k) acc += M[i * 128 + k] * M[k * 128 + j];
        O[e] = acc;
    }
}

// ---------- A4 = A2*A2  and  M1 = (I - 2A + A2)(I + A2) ----------
__global__ void k_step2(const float* __restrict__ A, const float* __restrict__ A2,
                        float* __restrict__ A4, float* __restrict__ M1) {
    int b = blockIdx.x;                          // 64 blocks
    if (b < 32) {
        int t = b * 256 + threadIdx.x;
        for (int e = t; e < 16384; e += 8192) {
            int i = e >> 7, j = e & 127;
            float acc = 0.f;
            for (int k = 0; k < 128; ++k) acc += A2[i * 128 + k] * A2[k * 128 + j];
            A4[e] = acc;
        }
    } else {
        int t = (b - 32) * 256 + threadIdx.x;
        for (int e = t; e < 16384; e += 8192) {
            int i = e >> 7, j = e & 127;
            float acc = 0.f;
            for (int k = 0; k < 128; ++k) {
                float bik = A2[i * 128 + k] - 2.0f * A[i * 128 + k] + (k == i ? 1.0f : 0.0f);
                float ckj = A2[k * 128 + j] + (k == j ? 1.0f : 0.0f);
                acc += bik * ckj;
            }
            M1[e] = acc;
        }
    }
}

// ---------- P = M1*(I + A4);  store Q = P - I as bf16 ----------
__global__ void k_finalP(const float* __restrict__ M1, const float* __restrict__ A4,
                         unsigned short* __restrict__ Qb) {
    int t = blockIdx.x * 256 + threadIdx.x;      // 32 blocks
    for (int e = t; e < 16384; e += 8192) {
        int i = e >> 7, j = e & 127;
        float acc = M1[e];
        for (int k = 0; k < 128; ++k) acc += M1[i * 128 + k] * A4[k * 128 + j];
        if (i == j) acc -= 1.0f;                 // Q = P - I
        Qb[e] = f2bf(acc);
    }
}

// ---------- async stage of one 64-token tile (32 KB) into LDS ----------
// LDS is linear in chunk index L (16 B chunks); global source is PRE-SWIZZLED:
// LDS[tok][pc] holds global chunk c = pc ^ (tok & 7)  (involution; rule #21).
__device__ __forceinline__ void stage_tile(const float* gbase, float* ldsbase,
                                           int wave, int lane) {
    #pragma unroll
    for (int i = 0; i < 8; ++i) {
        const int L = (i * 4 + wave) * 64 + lane;        // chunk index 0..2047
        const int tok = L >> 5, pc = L & 31;
        const int c = pc ^ (tok & 7);
        const float* gp = gbase + tok * E_DIM + c * 4;
        float* lp = ldsbase + (size_t)(i * 4 + wave) * 256;   // wave-uniform base
        __builtin_amdgcn_global_load_lds(
            (const __attribute__((address_space(1))) void*)gp,
            (__attribute__((address_space(3))) void*)lp, 16, 0, 0);
    }
}

// ---------- main fused kernel: out = RoPE(x + x*Q^T) ----------
// Q in REGISTERS (32 bh8 = 128 VGPR/lane, loaded once). LDS = x double buffer
// only (2 x 32 KB -> 2 blocks/CU). Per tile: STAGE(t+1) -> compute(t) -> barrier.
// Swapped MFMA: acc[t] = D[n][m]; lane holds token m (col) -> f4 epilogue.
__global__ __launch_bounds__(256, 2) void k_main(const float* __restrict__ x,
        const unsigned short* __restrict__ Qb,
        const float* __restrict__ csT,
        float* __restrict__ out) {
    __shared__ float xb[2][TOK_TILE * E_DIM];    // 2 x 32 KB

    const int wave = threadIdx.x >> 6;
    const int lane = threadIdx.x & 63;
    const int lhi = lane >> 4, llo = lane & 15;

    // Q fragments into registers: qf[t*4+kk] = Q[n=t*16+llo][k=kk*32+lhi*8 .. +7]
    bh8 qf[32];
    #pragma unroll
    for (int t = 0; t < 8; ++t) {
        #pragma unroll
        for (int kk = 0; kk < 4; ++kk) {
            qf[t * 4 + kk] = *(const bh8*)(Qb + (size_t)(t * 16 + llo) * E_DIM
                                              + kk * 32 + lhi * 8);
        }
    }

    const int tile0 = blockIdx.x * TILES_PER_BLOCK;
    stage_tile(x + (size_t)tile0 * TOK_TILE * E_DIM, &xb[0][0], wave, lane);
    __syncthreads();

    const int wtok = wave * 16 + llo;            // this lane's token within tile
    const int sw = wtok & 7;                     // swizzle key
    const float* xrow_lds_base = nullptr;        // (per-iter below)

    for (int tl = 0; tl < TILES_PER_BLOCK; ++tl) {
        const int cur = tl & 1;
        if (tl + 1 < TILES_PER_BLOCK)
            stage_tile(x + (size_t)(tile0 + tl + 1) * TOK_TILE * E_DIM,
                       &xb[cur ^ 1][0], wave, lane);

        const float* xcur = &xb[cur][0] + wtok * E_DIM;
        const int m = (tile0 + tl) * TOK_TILE + wtok;
        const int s = m & (S_LEN - 1);

        // x fragments from LDS (swizzled 16B chunks), convert to bf16
        bh8 frag[4];
        #pragma unroll
        for (int kk = 0; kk < 4; ++kk) {
            const int c0 = kk * 8 + lhi * 2;
            f4 v0 = *(const f4*)(xcur + ((c0)     ^ sw) * 4);
            f4 v1 = *(const f4*)(xcur + ((c0 + 1) ^ sw) * 4);
            bh8 a;
            #pragma unroll
            for (int j = 0; j < 4; ++j) {
                a[j]     = bfc(v0[j]);
                a[4 + j] = bfc(v1[j]);
            }
            frag[kk] = a;
        }

        f4 acc[8];
        #pragma unroll
        for (int t = 0; t < 8; ++t) { f4 z = {0.f, 0.f, 0.f, 0.f}; acc[t] = z; }

        #pragma unroll
        for (int kk = 0; kk < 4; ++kk) {
            #pragma unroll
            for (int t = 0; t < 8; ++t) {
                acc[t] = __builtin_amdgcn_mfma_f32_16x16x32_bf16(
                             qf[t * 4 + kk], frag[kk], acc[t], 0, 0, 0);
            }
        }

        // epilogue: xt = x + x*Q^T (x from LDS), rotate-half RoPE, f4 stores
        const float* csp = csT + (size_t)s * 128;
        float* orow = out + (size_t)m * E_DIM;
        #pragma unroll
        for (int t = 0; t < 4; ++t) {
            const int n0 = t * 16 + lhi * 4;     // 4 consecutive n in regs r=0..3
            const int cl = t * 4 + lhi;          // 16B chunk of cols n0..n0+3
            f4 xlo = *(const f4*)(xcur + (cl ^ sw) * 4);
            f4 xhi = *(const f4*)(xcur + ((16 + cl) ^ sw) * 4);
            f4 cs_lo = *(const f4*)(csp + n0);        // {cos f, sin f, cos f+1, sin f+1}
            f4 cs_hi = *(const f4*)(csp + 64 + n0);
            f4 olo, ohi;
            #pragma unroll
            for (int r = 0; r < 4; ++r) {
                float xt1 = acc[t][r] + xlo[r];          // n = n0+r
                float xt2 = acc[t + 4][r] + xhi[r];      // n+64
                float c1 = cs_lo[(r >> 1) * 2], s1 = cs_lo[(r >> 1) * 2 + 1];
                float c2 = cs_hi[(r >> 1) * 2], s2 = cs_hi[(r >> 1) * 2 + 1];
                olo[r] = xt1 * c1 - xt2 * s1;
                ohi[r] = xt2 * c2 + xt1 * s2;
            }
            *(f4*)(orow + n0) = olo;
            *(f4*)(orow + n0 + 64) = ohi;
        }

        __syncthreads();   // drains prefetch (vmcnt) + guards buffer reuse
    }
    (void)xrow_lds_base;
}

extern "C" void kernel_launch(void* const* d_in, const int* in_sizes, int n_in,
                              void* d_out, int out_size, void* d_ws, size_t ws_size,
                              hipStream_t stream) {
    const float* x   = (const float*)d_in[0];
    const float* pos = (const float*)d_in[1];
    const float* Sc  = (const float*)d_in[2];
    float* out = (float*)d_out;

    char* ws = (char*)d_ws;
    float* A            = (float*)(ws);                    // 64 KB
    float* A2           = (float*)(ws + 65536);            // 64 KB
    float* A4           = (float*)(ws + 131072);           // 64 KB
    float* M1           = (float*)(ws + 196608);           // 64 KB
    unsigned short* Qb  = (unsigned short*)(ws + 262144);  // 32 KB bf16
    float* csT          = (float*)(ws + 294912);           // 2 MB interleaved cos/sin

    k_prep<<<272, 256, 0, stream>>>(Sc, pos, A, csT);
    k_sq<<<32, 256, 0, stream>>>(A, A2);
    k_step2<<<64, 256, 0, stream>>>(A, A2, A4, M1);
    k_finalP<<<32, 256, 0, stream>>>(M1, A4, Qb);
    k_main<<<GRID_MAIN, 256, 0, stream>>>(x, Qb, csT, out);
}

// Round 7
// 80.202 us; speedup vs baseline: 1.5694x; 1.3545x over previous
//
#include <hip/hip_runtime.h>
#include <hip/hip_bf16.h>
#include <cstdint>
#include <cstddef>

// Problem constants (B=4, H=16, S=4096, E=128)
#define S_LEN 4096
#define E_DIM 128
#define NROWS (4 * 16 * 4096)   // 262144 token rows
#define TOK_TILE 64             // tokens per LDS tile (32 KB f32)
#define GRID_MAIN 512
#define T_TILES (NROWS / TOK_TILE / GRID_MAIN)   // 8

typedef __attribute__((ext_vector_type(8))) short bh8;   // 8 bf16 (4 VGPRs) MFMA frag
typedef __attribute__((ext_vector_type(4))) float f4;    // MFMA accumulator
typedef unsigned short u16;

__device__ __forceinline__ u16 f2bf(float f) {
    union { float f; uint32_t u; } v; v.f = f;
    uint32_t r = v.u + 0x7FFFu + ((v.u >> 16) & 1u);   // round-to-nearest-even
    return (u16)(r >> 16);
}
__device__ __forceinline__ short bfc(float f) {
    __hip_bfloat16 h = __float2bfloat16(f);
    return *reinterpret_cast<short*>(&h);
}
__device__ __forceinline__ float bf2f(u16 u) {
    union { uint32_t u; float f; } v; v.u = ((uint32_t)u) << 16;
    return v.f;
}

// ============================================================================
// Fused prologue: block 0 = Cayley chain via MFMA (1 CU, ~3 µs);
// blocks 1..16 = interleaved cos/sin table csT[s*128+2f]={cos,sin}.
//
// Antisymmetry trick: A^T=-A, A2/A4 symmetric => every B-operand column is
// +/- a row, so both MFMA operands are read as ROWS (mfmaRR(X,Y)=X*Y^T):
//   A2 = -RR(A,A);  A4 = RR(A2,A2);  Y1 = A+A2
//   R/2 = A2 + RR(A2,Y1) + RR(A4,Y1)        (= A2-A3+A4-A5+A6, err O(|A|^7))
//   Q   = P - I = -2A + 2*R/2*... = 2*(acc + A2 - A)  with acc = RR(A2,Y1)+RR(A4,Y1)
// ============================================================================
__device__ __forceinline__ bh8 ldsRow(const u16* M, int row, int c) {
    return *(const bh8*)(&M[row * 128 + ((c ^ (row & 15)) * 8)]);
}
__device__ __forceinline__ int swzIdx(int n, int m) {     // element (n,m) in swizzled row-major
    return n * 128 + (((m >> 3) ^ (n & 15)) * 8) + (m & 7);
}

__global__ __launch_bounds__(1024) void k_pro(const float* __restrict__ Sc,
        const float* __restrict__ pos, u16* __restrict__ Qb,
        float* __restrict__ csT) {
    if (blockIdx.x != 0) {
        int t = (blockIdx.x - 1) * 1024 + threadIdx.x;
        for (int e = t; e < S_LEN * 64; e += 16 * 1024) {
            int s = e >> 6, f = e & 63;
            float freq = exp2f(-0.20762050593046015f * (float)f);  // 10000^(-f/64)
            float sv, cv;
            sincosf(pos[s] * freq, &sv, &cv);
            csT[s * 128 + 2 * f]     = cv;
            csT[s * 128 + 2 * f + 1] = sv;
        }
        return;
    }
    __shared__ u16 Abf[128 * 128];
    __shared__ u16 A2bf[128 * 128];
    __shared__ u16 Y1bf[128 * 128];
    __shared__ u16 A4bf[128 * 128];

    // A = (Sc - Sc^T)/2 -> bf16 swizzled LDS
    for (int e = threadIdx.x; e < 16384; e += 1024) {
        int i = e >> 7, j = e & 127;
        float a = 0.5f * (Sc[i * 128 + j] - Sc[j * 128 + i]);
        Abf[swzIdx(i, j)] = f2bf(a);
    }
    __syncthreads();

    const int wave = threadIdx.x >> 6;      // 16 waves
    const int lane = threadIdx.x & 63;
    const int lhi = lane >> 4, llo = lane & 15;
    const int sm = wave & 7;                // m-strip (16 cols)
    const int nh = wave >> 3;               // n half (4 n-tiles)

    // ---- pass 1: acc = RR(A,A); A2 = -acc; Y1 = A + A2 ----
    {
        f4 acc[4];
        #pragma unroll
        for (int t = 0; t < 4; ++t) { f4 z = {0.f,0.f,0.f,0.f}; acc[t] = z; }
        #pragma unroll
        for (int kk = 0; kk < 4; ++kk) {
            bh8 yf = ldsRow(Abf, sm * 16 + llo, kk * 4 + lhi);
            #pragma unroll
            for (int t = 0; t < 4; ++t) {
                bh8 xf = ldsRow(Abf, (nh * 4 + t) * 16 + llo, kk * 4 + lhi);
                acc[t] = __builtin_amdgcn_mfma_f32_16x16x32_bf16(xf, yf, acc[t], 0, 0, 0);
            }
        }
        __syncthreads();   // all reads of Abf done before writes below race? (different arrays; just order)
        #pragma unroll
        for (int t = 0; t < 4; ++t) {
            #pragma unroll
            for (int r = 0; r < 4; ++r) {
                int n = (nh * 4 + t) * 16 + lhi * 4 + r, m = sm * 16 + llo;
                float a2 = -acc[t][r];
                A2bf[swzIdx(n, m)] = f2bf(a2);
                Y1bf[swzIdx(n, m)] = f2bf(a2 + bf2f(Abf[swzIdx(n, m)]));
            }
        }
    }
    __syncthreads();
    // ---- pass 2: A4 = RR(A2,A2) ----
    {
        f4 acc[4];
        #pragma unroll
        for (int t = 0; t < 4; ++t) { f4 z = {0.f,0.f,0.f,0.f}; acc[t] = z; }
        #pragma unroll
        for (int kk = 0; kk < 4; ++kk) {
            bh8 yf = ldsRow(A2bf, sm * 16 + llo, kk * 4 + lhi);
            #pragma unroll
            for (int t = 0; t < 4; ++t) {
                bh8 xf = ldsRow(A2bf, (nh * 4 + t) * 16 + llo, kk * 4 + lhi);
                acc[t] = __builtin_amdgcn_mfma_f32_16x16x32_bf16(xf, yf, acc[t], 0, 0, 0);
            }
        }
        #pragma unroll
        for (int t = 0; t < 4; ++t)
            #pragma unroll
            for (int r = 0; r < 4; ++r) {
                int n = (nh * 4 + t) * 16 + lhi * 4 + r, m = sm * 16 + llo;
                A4bf[swzIdx(n, m)] = f2bf(acc[t][r]);
            }
    }
    __syncthreads();
    // ---- pass 3: acc = RR(A2,Y1) + RR(A4,Y1); Q = 2*(acc + A2 - A) ----
    {
        f4 acc[4];
        #pragma unroll
        for (int t = 0; t < 4; ++t) { f4 z = {0.f,0.f,0.f,0.f}; acc[t] = z; }
        #pragma unroll
        for (int kk = 0; kk < 4; ++kk) {
            bh8 yf = ldsRow(Y1bf, sm * 16 + llo, kk * 4 + lhi);
            #pragma unroll
            for (int t = 0; t < 4; ++t) {
                bh8 xf = ldsRow(A2bf, (nh * 4 + t) * 16 + llo, kk * 4 + lhi);
                acc[t] = __builtin_amdgcn_mfma_f32_16x16x32_bf16(xf, yf, acc[t], 0, 0, 0);
            }
        }
        #pragma unroll
        for (int kk = 0; kk < 4; ++kk) {
            bh8 yf = ldsRow(Y1bf, sm * 16 + llo, kk * 4 + lhi);
            #pragma unroll
            for (int t = 0; t < 4; ++t) {
                bh8 xf = ldsRow(A4bf, (nh * 4 + t) * 16 + llo, kk * 4 + lhi);
                acc[t] = __builtin_amdgcn_mfma_f32_16x16x32_bf16(xf, yf, acc[t], 0, 0, 0);
            }
        }
        #pragma unroll
        for (int t = 0; t < 4; ++t)
            #pragma unroll
            for (int r = 0; r < 4; ++r) {
                int n = (nh * 4 + t) * 16 + lhi * 4 + r, m = sm * 16 + llo;
                float q = 2.0f * (acc[t][r] + bf2f(A2bf[swzIdx(n, m)])
                                            - bf2f(Abf[swzIdx(n, m)]));
                Qb[n * 128 + m] = f2bf(q);
            }
    }
}

// ---------- async stage of one 64-token tile (32 KB) into LDS ----------
// LDS linear in 16B-chunk index; global source pre-swizzled (rule #21):
// LDS[tok][pc] holds global chunk c = pc ^ (tok & 7).
__device__ __forceinline__ void stage_tile(const float* gbase, float* ldsbase,
                                           int wave, int lane) {
    #pragma unroll
    for (int i = 0; i < 8; ++i) {
        const int L = (i * 4 + wave) * 64 + lane;        // chunk index 0..2047
        const int tok = L >> 5, pc = L & 31;
        const int c = pc ^ (tok & 7);
        const float* gp = gbase + tok * E_DIM + c * 4;
        float* lp = ldsbase + (size_t)(i * 4 + wave) * 256;   // wave-uniform base
        __builtin_amdgcn_global_load_lds(
            (const __attribute__((address_space(1))) void*)gp,
            (__attribute__((address_space(3))) void*)lp, 16, 0, 0);
    }
}

// ============================================================================
// Main fused kernel: out = RoPE(x + x*Q^T)
// Counted-vmcnt pipeline (T4): per iter, VMEM program order is
//   [A] 8 csT loads  [B] 8 global_load_lds (stage t+1)  [C] 8 f4 stores
// End-of-iter "s_waitcnt vmcnt(8)" => stage(t+1) complete (B older than C),
// stores still in flight. Raw s_barrier (no compiler vmcnt(0) drain).
// Q in LDS (R3 swizzle); x double-buffered (96 KB total, 1 block/CU).
// ============================================================================
__global__ __launch_bounds__(256, 1) void k_main(const float* __restrict__ x,
        const u16* __restrict__ Qb, const float* __restrict__ csT,
        float* __restrict__ out) {
    __shared__ u16 Plds[128 * 128];          // 32 KB Q
    __shared__ float xb[2][TOK_TILE * E_DIM];  // 2 x 32 KB x tiles

    // stage Q (R3 scheme: chunk c of row stored at c ^ (row&15))
    #pragma unroll
    for (int i = 0; i < 8; ++i) {
        int chunk = i * 256 + threadIdx.x;
        int row = chunk >> 4, c = chunk & 15;
        int pc = c ^ (row & 15);
        bh8 v = *(const bh8*)(Qb + chunk * 8);
        *(bh8*)(&Plds[row * 128 + pc * 8]) = v;
    }

    const int wave = threadIdx.x >> 6;
    const int lane = threadIdx.x & 63;
    const int lhi = lane >> 4, llo = lane & 15;
    const int wtok = wave * 16 + llo;        // this lane's token within tile
    const int sw = wtok & 7;                 // x-swizzle key
    const int tile0 = blockIdx.x * T_TILES;

    stage_tile(x + (size_t)tile0 * TOK_TILE * E_DIM, &xb[0][0], wave, lane);
    __syncthreads();                          // one-time full drain (vmcnt 0)

    for (int tl = 0; tl < T_TILES; ++tl) {
        const int cur = tl & 1;
        const int m = (tile0 + tl) * TOK_TILE + wtok;
        const int s = m & (S_LEN - 1);

        // [A] csT loads -> regs (issued first so their waits never drain [B])
        f4 cs[8];
        const float* csp = csT + (size_t)s * 128;
        #pragma unroll
        for (int t = 0; t < 4; ++t) {
            cs[t]     = *(const f4*)(csp + t * 16 + lhi * 4);
            cs[4 + t] = *(const f4*)(csp + 64 + t * 16 + lhi * 4);
        }
        __builtin_amdgcn_sched_barrier(0);

        // [B] stage next tile into the other buffer
        if (tl + 1 < T_TILES)
            stage_tile(x + (size_t)(tile0 + tl + 1) * TOK_TILE * E_DIM,
                       &xb[cur ^ 1][0], wave, lane);
        __builtin_amdgcn_sched_barrier(0);

        // compute tile t from xb[cur]
        const float* xcur = &xb[cur][0] + wtok * E_DIM;

        bh8 frag[4];
        #pragma unroll
        for (int kk = 0; kk < 4; ++kk) {
            const int c0 = kk * 8 + lhi * 2;
            f4 v0 = *(const f4*)(xcur + ((c0)     ^ sw) * 4);
            f4 v1 = *(const f4*)(xcur + ((c0 + 1) ^ sw) * 4);
            bh8 a;
            #pragma unroll
            for (int j = 0; j < 4; ++j) { a[j] = bfc(v0[j]); a[4 + j] = bfc(v1[j]); }
            frag[kk] = a;
        }

        f4 acc[8];
        #pragma unroll
        for (int t = 0; t < 8; ++t) { f4 z = {0.f, 0.f, 0.f, 0.f}; acc[t] = z; }
        #pragma unroll
        for (int kk = 0; kk < 4; ++kk) {
            #pragma unroll
            for (int t = 0; t < 8; ++t) {
                int pc = (kk * 4 + lhi) ^ llo;       // Q row&15 == llo
                bh8 qfrag = *(const bh8*)(&Plds[(t * 16 + llo) * 128 + pc * 8]);
                acc[t] = __builtin_amdgcn_mfma_f32_16x16x32_bf16(qfrag, frag[kk], acc[t], 0, 0, 0);
            }
        }

        // epilogue + [C] stores (8 f4, youngest VMEM ops of the iter)
        float* orow = out + (size_t)m * E_DIM;
        #pragma unroll
        for (int t = 0; t < 4; ++t) {
            const int n0 = t * 16 + lhi * 4;
            const int cl = t * 4 + lhi;              // 16B chunk of cols n0..n0+3
            f4 xlo = *(const f4*)(xcur + (cl ^ sw) * 4);
            f4 xhi = *(const f4*)(xcur + ((16 + cl) ^ sw) * 4);
            f4 olo, ohi;
            #pragma unroll
            for (int r = 0; r < 4; ++r) {
                float xt1 = acc[t][r] + xlo[r];
                float xt2 = acc[t + 4][r] + xhi[r];
                float c1 = cs[t][(r >> 1) * 2],     s1 = cs[t][(r >> 1) * 2 + 1];
                float c2 = cs[4 + t][(r >> 1) * 2], s2 = cs[4 + t][(r >> 1) * 2 + 1];
                olo[r] = xt1 * c1 - xt2 * s1;
                ohi[r] = xt2 * c2 + xt1 * s2;
            }
            *(f4*)(orow + n0) = olo;
            *(f4*)(orow + n0 + 64) = ohi;
        }

        // end of iter: wait until only the 8 stores may remain in flight,
        // then raw barrier (no full vmcnt-0 drain).
        __builtin_amdgcn_sched_barrier(0);
        asm volatile("s_waitcnt vmcnt(8)" ::: "memory");
        __builtin_amdgcn_sched_barrier(0);
        __builtin_amdgcn_s_barrier();
        __builtin_amdgcn_sched_barrier(0);
    }
}

extern "C" void kernel_launch(void* const* d_in, const int* in_sizes, int n_in,
                              void* d_out, int out_size, void* d_ws, size_t ws_size,
                              hipStream_t stream) {
    const float* x   = (const float*)d_in[0];
    const float* pos = (const float*)d_in[1];
    const float* Sc  = (const float*)d_in[2];
    float* out = (float*)d_out;

    char* ws = (char*)d_ws;
    u16* Qb     = (u16*)(ws);              // 32 KB bf16 Q = P - I
    float* csT  = (float*)(ws + 32768);    // 2 MB interleaved cos/sin

    k_pro<<<17, 1024, 0, stream>>>(Sc, pos, Qb, csT);
    k_main<<<GRID_MAIN, 256, 0, stream>>>(x, Qb, csT, out);
}